// Round 6
// baseline (663.625 us; speedup 1.0000x reference)
//
#include <hip/hip_runtime.h>

typedef _Float16 h2 __attribute__((ext_vector_type(2)));
typedef float    f2 __attribute__((ext_vector_type(2)));

#define NTHREADS 256
#define RW 128      // region width (cols) = 64 lanes x 2
#define RH 48       // region height (rows held in registers)
#define TW 104      // output tile width  = RW - 24
#define TH 24       // output tile height = RH - 24
#define NITER 11    // 1 initial + NUM_ITER=10
#define IMG 1024
#define GX 10       // ceil(1024/104)
#define GY 43       // ceil(1024/24)
#define NWAVES (GX*GY*16)          // 6880
#define NBLOCKS (NWAVES/(NTHREADS/64))

__device__ __forceinline__ unsigned h2u_(h2 v){ union {h2 h; unsigned u;} c; c.h=v; return c.u; }
__device__ __forceinline__ h2 u2h_(unsigned u){ union {h2 h; unsigned u;} c; c.u=u; return c.h; }
__device__ __forceinline__ h2 pmin(h2 a, h2 b){ return __builtin_elementwise_min(a,b); }
__device__ __forceinline__ h2 pmax(h2 a, h2 b){ return __builtin_elementwise_max(a,b); }

// Packed-f16 wave-autonomous soft-skeleton. Lane = 2 adjacent columns (one
// v_pk register). Vertical 3-min/max: registers. Horizontal: 2 shfl + 2
// alignbit per row for all 128 cols. No LDS, no barriers.
// ws[0]=sum(skel_pred*target) ws[1]=sum(skel_pred)
// ws[2]=sum(skel_target*sigmoid(pred)) ws[3]=sum(skel_target)
__global__ __launch_bounds__(NTHREADS, 4)
void cldice_main(const float* __restrict__ pred,
                 const float* __restrict__ target,
                 double* __restrict__ ws)
{
    const int tid  = threadIdx.x;
    const int lane = tid & 63;
    const int wid  = blockIdx.x * (NTHREADS/64) + (tid >> 6);
    const int tx = wid % GX;
    const int t2 = wid / GX;
    const int ty = t2 % GY;
    const int zp = t2 / GY;          // 0..15
    const int b = zp >> 1, phase = zp & 1;

    const int ox = tx * TW - 12;
    const int oy = ty * TH - 12;
    const size_t base = (size_t)b * (size_t)(IMG * IMG);
    const float* __restrict__ src = phase ? target : pred;
    const float* __restrict__ oth = phase ? pred : target;

    const unsigned PINF2 = 0x7C007C00u;   // +inf | +inf (f16x2)
    const unsigned NINF2 = 0xFC00FC00u;   // -inf | -inf

    const int gx0 = ox + 2 * lane;        // even; col pair (gx0, gx0+1)
    unsigned colm = 0u;                   // per-half image-valid mask
    if ((unsigned)gx0       < (unsigned)IMG) colm |= 0x0000FFFFu;
    if ((unsigned)(gx0 + 1) < (unsigned)IMG) colm |= 0xFFFF0000u;
    const bool xint = (ox >= 0) && (ox + RW <= IMG);

    // ---- load region; image-OOB -> +inf (erode pad identity)
    h2 e[RH];
#pragma unroll
    for (int j = 0; j < RH; ++j) {
        const int gy = oy + j;
        unsigned ebits = PINF2;
        if ((unsigned)gy < (unsigned)IMG) {
            float v0 = 0.f, v1 = 0.f;
            if (xint) {
                f2 v = *(const f2*)(src + base + (size_t)gy * IMG + gx0);
                v0 = v[0]; v1 = v[1];
            } else {
                if ((unsigned)gx0       < (unsigned)IMG) v0 = src[base + (size_t)gy * IMG + gx0];
                if ((unsigned)(gx0 + 1) < (unsigned)IMG) v1 = src[base + (size_t)gy * IMG + gx0 + 1];
            }
            if (!phase) {
                v0 = 1.f / (1.f + __expf(-v0));
                v1 = 1.f / (1.f + __expf(-v1));
            }
            h2 hv; hv[0] = (_Float16)v0; hv[1] = (_Float16)v1;
            const unsigned hb = h2u_(hv);
            ebits = (colm & hb) | (~colm & PINF2);   // v_bfi
        }
        e[j] = u2h_(ebits);
    }

    h2 skel[TH];
#pragma unroll
    for (int k = 0; k < TH; ++k) skel[k] = u2h_(0u);
    const h2 zero2 = u2h_(0u);

    // Invariant: at iteration start e[] holds +inf at image-OOB positions.
    // Validity shrinks 1 row/col per erosion; skel interior rows [12,35],
    // cols [12,115] need er rows/cols [11,36]/[11,116] at it=10 = exact.
#pragma unroll 1
    for (int it = 0; it < NITER; ++it) {
        h2 ep = e[0], ec = e[1];
        h2 nm2 = u2h_(NINF2), nm1 = u2h_(NINF2);
#pragma unroll
        for (int j = 1; j <= RH - 2; ++j) {
            const h2 en = e[j + 1];
            // erode: vertical 3-min (regs) then horizontal 3-min (shfl+align)
            const h2 vm = pmin(pmin(ep, ec), en);
            const unsigned u = h2u_(vm);
            const unsigned L = __shfl_up(u, 1);
            const unsigned R = __shfl_down(u, 1);
            const h2 P = u2h_((L >> 16) | (u << 16));   // (L.hi, u.lo)
            const h2 N = u2h_((u >> 16) | (R << 16));   // (u.hi, R.lo)
            const h2 er = pmin(pmin(P, vm), N);
            const unsigned erb = h2u_(er);
            const unsigned m = ((unsigned)(oy + j) < (unsigned)IMG) ? colm : 0u;
            if (j >= 11 && j <= 36) {
                // open input: er with image-OOB -> -inf (maxpool pad)
                const h2 ner = u2h_((m & erb) | (~m & NINF2));
                if (j >= 13) {
                    // open[j-1] = hmax3(vmax3(ner[j-2..j]))
                    const h2 om = pmax(pmax(nm2, nm1), ner);
                    const unsigned uo = h2u_(om);
                    const unsigned Lo = __shfl_up(uo, 1);
                    const unsigned Ro = __shfl_down(uo, 1);
                    const h2 Po = u2h_((Lo >> 16) | (uo << 16));
                    const h2 No = u2h_((uo >> 16) | (Ro << 16));
                    const h2 op = pmax(pmax(Po, om), No);
                    const h2 d  = pmax(ep - op, zero2);   // ep = e_orig[j-1]
                    const int k = j - 13;                 // 0..23
                    skel[k] = skel[k] + pmax(d - skel[k] * d, zero2);
                }
                nm2 = nm1; nm1 = ner;
            }
            // e_next = er; restore +inf at image-OOB for next erode
            e[j] = u2h_((m & erb) | (~m & PINF2));
            ep = ec; ec = en;
        }
    }

    // ---- sums over interior (region rows 12..35, lanes 6..57 = cols 12..115)
    float spf = 0.f, ssf = 0.f;
    const bool laneIn = (lane >= 6) && (lane <= 57);
#pragma unroll
    for (int k = 0; k < TH; ++k) {
        const int gy = oy + 12 + k;
        const unsigned msum = (laneIn && (unsigned)gy < (unsigned)IMG) ? colm : 0u;
        const h2 sh = u2h_(msum & h2u_(skel[k]));   // invalid halves -> +0
        const float s0 = (float)sh[0], s1 = (float)sh[1];
        const int gyc = min(max(gy, 0), IMG - 1);
        const int gxc = min(max(gx0, 0), IMG - 2);
        f2 o = *(const f2*)(oth + base + (size_t)gyc * IMG + gxc);
        float x0 = o[0], x1 = o[1];
        if (phase) {
            x0 = 1.f / (1.f + __expf(-x0));
            x1 = 1.f / (1.f + __expf(-x1));
        }
        spf += s0 * x0 + s1 * x1;
        ssf += s0 + s1;
    }
    double sp = (double)spf, ss = (double)ssf;
#pragma unroll
    for (int off = 32; off > 0; off >>= 1) {
        sp += __shfl_down(sp, off);
        ss += __shfl_down(ss, off);
    }
    if (lane == 0) {
        atomicAdd(&ws[phase * 2],     sp);
        atomicAdd(&ws[phase * 2 + 1], ss);
    }
}

__global__ void cldice_zero(double* __restrict__ ws) {
    if (threadIdx.x < 4) ws[threadIdx.x] = 0.0;
}

__global__ void cldice_final(const double* __restrict__ ws,
                             float* __restrict__ out) {
    if (threadIdx.x == 0 && blockIdx.x == 0) {
        double tprec = (ws[0] + 1.0) / (ws[1] + 1.0);
        double tsens = (ws[2] + 1.0) / (ws[3] + 1.0);
        double cl = 2.0 * tprec * tsens / (tprec + tsens + 1e-7);
        out[0] = (float)(1.0 - cl);
    }
}

extern "C" void kernel_launch(void* const* d_in, const int* in_sizes, int n_in,
                              void* d_out, int out_size, void* d_ws, size_t ws_size,
                              hipStream_t stream) {
    const float* pred   = (const float*)d_in[0];
    const float* target = (const float*)d_in[1];
    double* ws = (double*)d_ws;
    float* out = (float*)d_out;

    cldice_zero<<<dim3(1), dim3(64), 0, stream>>>(ws);
    cldice_main<<<dim3(NBLOCKS), dim3(NTHREADS), 0, stream>>>(pred, target, ws);
    cldice_final<<<dim3(1), dim3(64), 0, stream>>>(ws, out);
}

// Round 7
// 288.609 us; speedup vs baseline: 2.2994x; 2.2994x over previous
//
#include <hip/hip_runtime.h>

typedef _Float16 h2 __attribute__((ext_vector_type(2)));
typedef float    f2 __attribute__((ext_vector_type(2)));

#define NTHREADS 256
#define TILE 64
#define HALO 12
#define REGN 88      // region rows (= cols)
#define NH2  44      // h2 cells per region row (88 cols)
#define STRH 52      // LDS row stride in h2 (208 B; 52%32=20 bank stagger)
#define NITER 11     // 1 initial + NUM_ITER=10
#define IMG 1024
#define NTILE 16
#define KROWS 4      // erode rows per pass-1 job
#define NCH 11       // 8-col chunks per row (44 h2 / 4)

#define PINF2 0x7C007C00u
#define NINF2 0xFC00FC00u

__device__ __forceinline__ h2 H2c(unsigned u){ return __builtin_bit_cast(h2, u); }
__device__ __forceinline__ unsigned U32c(h2 h){ return __builtin_bit_cast(unsigned, h); }
__device__ __forceinline__ h2 pmin2(h2 a, h2 b){ return __builtin_elementwise_min(a,b); }
__device__ __forceinline__ h2 pmax2(h2 a, h2 b){ return __builtin_elementwise_max(a,b); }

// ws[0]=sum(skel_pred*target) ws[1]=sum(skel_pred)
// ws[2]=sum(skel_target*sigmoid(pred)) ws[3]=sum(skel_target)
__global__ __launch_bounds__(NTHREADS, 4)
void cldice_main(const float* __restrict__ pred,
                 const float* __restrict__ target,
                 double* __restrict__ ws)
{
    __shared__ __align__(16) h2 S[REGN][STRH];   // 18304 B -> 8 blocks/CU
    __shared__ double red[8];

    const int tid  = threadIdx.x;
    const int lane = tid & 63;
    const int tx = blockIdx.x, ty = blockIdx.y;
    const int b = blockIdx.z >> 1, phase = blockIdx.z & 1;
    const int oy = ty*TILE - HALO, ox = tx*TILE - HALO;
    const size_t base = (size_t)b * (size_t)(IMG*IMG);
    const float* __restrict__ src = phase ? target : pred;
    const float* __restrict__ oth = phase ? pred : target;

    const bool border = (tx==0) || (tx==NTILE-1) || (ty==0) || (ty==NTILE-1);
    const int xloh = (tx==0) ? 6 : 0;            // first in-image h2 col
    const int xhih = (tx==NTILE-1) ? 38 : NH2;   // one past last in-image h2
    const int ylo  = (ty==0) ? HALO : 0;
    const int yhi  = (ty==NTILE-1) ? REGN-HALO : REGN;

    // ---- initial load: f32 pairs -> (sigmoid) -> packed f16; OOB -> +inf
    for (int i = tid; i < REGN*NH2; i += NTHREADS) {
        const int ly = i / NH2, lc = i - ly*NH2;
        const int gy = oy + ly, gx = ox + 2*lc;   // gx even; pair in/out together
        unsigned eb = PINF2;
        if ((unsigned)gy < (unsigned)IMG && (unsigned)gx < (unsigned)IMG) {
            f2 v = *(const f2*)(src + base + (size_t)gy*IMG + gx);
            float v0 = v[0], v1 = v[1];
            if (!phase) { v0 = 1.f/(1.f+__expf(-v0)); v1 = 1.f/(1.f+__expf(-v1)); }
            h2 hv; hv[0] = (_Float16)v0; hv[1] = (_Float16)v1;
            eb = U32c(hv);
        }
        S[ly][lc] = H2c(eb);
    }
    __syncthreads();

    // pass-2 patch: 8 cols x 2 rows per thread (covers interior 64x64)
    const int lx0h = 6 + 4*(tid & 7);        // own h2 base (cols 12..75)
    const int ly0  = HALO + 2*(tid >> 3);    // rows ly0, ly0+1
    const int bh   = lx0h - 2;               // 16B-aligned window base (h2)

    // pass-1 job mapping: chunk = 4 h2 (8 cols), KROWS rows
    const int rb  = tid / NCH;
    const int ci  = tid - rb*NCH;
    const int x0h = 4*ci;
    const bool lv = (ci != 0) && (lane != 0);
    const bool rv = (ci != NCH-1) && (lane != 63);
    const int lidx = (ci == 0) ? 0 : x0h - 1;
    const int ridx = (ci == NCH-1) ? NH2-1 : x0h + 4;

    unsigned cm[4];   // per-h2-pair in-image mask (border blocks)
#pragma unroll
    for (int i2 = 0; i2 < 4; ++i2)
        cm[i2] = ((x0h+i2) >= xloh && (x0h+i2) < xhih) ? 0xFFFFFFFFu : 0u;

    const h2 z2 = H2c(0u);
    h2 sk0[4], sk1[4];
#pragma unroll
    for (int i2 = 0; i2 < 4; ++i2) { sk0[i2] = z2; sk1[i2] = z2; }

    // horizontal 3-min over a row of 4 h2 (+ neighbors via shfl / scalar LDS)
    auto ROWH = [&](int r, h2 out[4]) {
        uint4 U = *(const uint4*)&S[r][x0h];
        unsigned u0 = U.x, u1 = U.y, u2 = U.z, u3 = U.w;
        unsigned lb = __shfl_up(u3, 1);
        unsigned rn = __shfl_down(u0, 1);
        if (!lv) lb = U32c(S[r][lidx]);
        if (!rv) rn = U32c(S[r][ridx]);
        const unsigned p0 = (lb>>16)|(u0<<16);
        const unsigned p1 = (u0>>16)|(u1<<16);
        const unsigned p2 = (u1>>16)|(u2<<16);
        const unsigned p3 = (u2>>16)|(u3<<16);
        const unsigned p4 = (u3>>16)|(rn<<16);
        out[0] = pmin2(pmin2(H2c(p0), H2c(u0)), H2c(p1));
        out[1] = pmin2(pmin2(H2c(p1), H2c(u1)), H2c(p2));
        out[2] = pmin2(pmin2(H2c(p2), H2c(u2)), H2c(p3));
        out[3] = pmin2(pmin2(H2c(p3), H2c(u3)), H2c(p4));
    };

#pragma unroll 1
    for (int it = 0; it < NITER; ++it) {
        const int row0 = it + 1, rowEnd = 87 - it;
        const int nrb = (rowEnd - row0 + KROWS - 1) / KROWS;
        const bool act = tid < NCH*nrb;
        const int r0 = row0 + rb*KROWS;

        // ---- pass 1: erode into registers (hmin per row, vertical slide)
        h2 er_[KROWS][4];
        if (act) {
            h2 hmA[4], hmB[4], hmC[4];
            ROWH(r0 - 1, hmA);
            ROWH(r0,     hmB);
#pragma unroll
            for (int jj = 0; jj < KROWS; ++jj) {
                ROWH(min(r0 + jj + 1, REGN - 1), hmC);
#pragma unroll
                for (int i2 = 0; i2 < 4; ++i2) {
                    er_[jj][i2] = pmin2(pmin2(hmA[i2], hmB[i2]), hmC[i2]);
                    hmA[i2] = hmB[i2]; hmB[i2] = hmC[i2];
                }
            }
        }

        // own-patch pre-erode e (for delta after overwrite)
        uint4 A0 = *(const uint4*)&S[ly0][bh];
        uint4 B0 = *(const uint4*)&S[ly0][bh+4];
        uint4 A1 = *(const uint4*)&S[ly0+1][bh];
        uint4 B1 = *(const uint4*)&S[ly0+1][bh+4];
        h2 ep0[4] = {H2c(A0.z), H2c(A0.w), H2c(B0.x), H2c(B0.y)};
        h2 ep1[4] = {H2c(A1.z), H2c(A1.w), H2c(B1.x), H2c(B1.y)};
        __syncthreads();   // all reads of e done

        // ---- write back er; border: image-OOB halves -> -inf (maxpool pad)
        if (act) {
#pragma unroll
            for (int jj = 0; jj < KROWS; ++jj) {
                const int r = r0 + jj;
                if (r < rowEnd) {
                    unsigned w0 = U32c(er_[jj][0]), w1 = U32c(er_[jj][1]);
                    unsigned w2 = U32c(er_[jj][2]), w3 = U32c(er_[jj][3]);
                    if (border) {
                        const unsigned rm = (r >= ylo && r < yhi) ? 0xFFFFFFFFu : 0u;
                        const unsigned m0 = cm[0]&rm, m1 = cm[1]&rm,
                                       m2 = cm[2]&rm, m3 = cm[3]&rm;
                        w0 = (m0 & w0) | (~m0 & NINF2);
                        w1 = (m1 & w1) | (~m1 & NINF2);
                        w2 = (m2 & w2) | (~m2 & NINF2);
                        w3 = (m3 & w3) | (~m3 & NINF2);
                    }
                    uint4 W; W.x = w0; W.y = w1; W.z = w2; W.w = w3;
                    *(uint4*)&S[r][x0h] = W;
                }
            }
        }
        __syncthreads();   // er visible

        // ---- pass 2: open = maxpool(er); delta; skel (aligned window, no shfl)
        {
            unsigned a0[6], a1[6], a2[6];
            auto LD6 = [&](int r, unsigned a[6]) {
                uint4 A = *(const uint4*)&S[r][bh];
                uint4 B = *(const uint4*)&S[r][bh+4];
                a[0]=A.y; a[1]=A.z; a[2]=A.w; a[3]=B.x; a[4]=B.y; a[5]=B.z;
            };
            LD6(ly0-1, a0); LD6(ly0, a1); LD6(ly0+1, a2);
            unsigned om0[6], om1[6];
#pragma unroll
            for (int k = 0; k < 6; ++k)
                om0[k] = U32c(pmax2(pmax2(H2c(a0[k]), H2c(a1[k])), H2c(a2[k])));
            LD6(ly0+2, a0);
#pragma unroll
            for (int k = 0; k < 6; ++k)
                om1[k] = U32c(pmax2(pmax2(H2c(a1[k]), H2c(a2[k])), H2c(a0[k])));

            auto HOP = [&](const unsigned m[6], const h2 ep[4], h2 sk[4]) {
                const unsigned p0 = (m[0]>>16)|(m[1]<<16);
                const unsigned p1 = (m[1]>>16)|(m[2]<<16);
                const unsigned p2 = (m[2]>>16)|(m[3]<<16);
                const unsigned p3 = (m[3]>>16)|(m[4]<<16);
                const unsigned p4 = (m[4]>>16)|(m[5]<<16);
                h2 op, d;
                op = pmax2(pmax2(H2c(p0), H2c(m[1])), H2c(p1));
                d  = pmax2(ep[0]-op, z2); sk[0] = sk[0] + pmax2(d - sk[0]*d, z2);
                op = pmax2(pmax2(H2c(p1), H2c(m[2])), H2c(p2));
                d  = pmax2(ep[1]-op, z2); sk[1] = sk[1] + pmax2(d - sk[1]*d, z2);
                op = pmax2(pmax2(H2c(p2), H2c(m[3])), H2c(p3));
                d  = pmax2(ep[2]-op, z2); sk[2] = sk[2] + pmax2(d - sk[2]*d, z2);
                op = pmax2(pmax2(H2c(p3), H2c(m[4])), H2c(p4));
                d  = pmax2(ep[3]-op, z2); sk[3] = sk[3] + pmax2(d - sk[3]*d, z2);
            };
            HOP(om0, ep0, sk0);
            HOP(om1, ep1, sk1);
        }

        // ---- border: restore +inf at OOB cells inside next read range
        if (border && it != NITER-1) {
            __syncthreads();
            const int lo = it + 1, hi = 86 - it;
            if (tx == 0) {
                const int r = lo + tid;
                if (r <= hi) for (int c = lo>>1; c <= 5; ++c) S[r][c] = H2c(PINF2);
            }
            if (tx == NTILE-1) {
                const int r = lo + tid;
                const int chi = hi >> 1;
                if (r <= hi) for (int c = 38; c <= chi; ++c) S[r][c] = H2c(PINF2);
            }
            if (ty == 0) {
                const int clo = lo>>1, chi = hi>>1;
                for (int i = tid; i < 12*NH2; i += NTHREADS) {
                    const int r = lo + i / NH2, c = i - (i/NH2)*NH2;
                    if (r <= 11 && c >= clo && c <= chi) S[r][c] = H2c(PINF2);
                }
            }
            if (ty == NTILE-1) {
                const int clo = lo>>1, chi = hi>>1;
                for (int i = tid; i < 12*NH2; i += NTHREADS) {
                    const int r = 76 + i / NH2, c = i - (i/NH2)*NH2;
                    if (r <= hi && c >= clo && c <= chi) S[r][c] = H2c(PINF2);
                }
            }
            __syncthreads();
        }
    }

    // ---- sums: sp = sum(skel * other), ss = sum(skel)   (all cells in-image)
    float spf = 0.f, ssf = 0.f;
    const float* rp = oth + base + (size_t)(oy + ly0)*IMG + (ox + 2*lx0h);
#pragma unroll
    for (int rr = 0; rr < 2; ++rr) {
#pragma unroll
        for (int i2 = 0; i2 < 4; ++i2) {
            f2 o = *(const f2*)(rp + (size_t)rr*IMG + 2*i2);
            float x0 = o[0], x1 = o[1];
            if (phase) { x0 = 1.f/(1.f+__expf(-x0)); x1 = 1.f/(1.f+__expf(-x1)); }
            const h2 s = rr ? sk1[i2] : sk0[i2];
            spf += (float)s[0]*x0 + (float)s[1]*x1;
            ssf += (float)s[0] + (float)s[1];
        }
    }
    double sp = (double)spf, ss = (double)ssf;
#pragma unroll
    for (int off = 32; off > 0; off >>= 1) {
        sp += __shfl_down(sp, off);
        ss += __shfl_down(ss, off);
    }
    const int wv = tid >> 6;
    if (lane == 0) { red[2*wv] = sp; red[2*wv+1] = ss; }
    __syncthreads();
    if (tid == 0) {
        atomicAdd(&ws[phase*2],     red[0]+red[2]+red[4]+red[6]);
        atomicAdd(&ws[phase*2+1],   red[1]+red[3]+red[5]+red[7]);
    }
}

__global__ void cldice_zero(double* __restrict__ ws) {
    if (threadIdx.x < 4) ws[threadIdx.x] = 0.0;
}

__global__ void cldice_final(const double* __restrict__ ws,
                             float* __restrict__ out) {
    if (threadIdx.x == 0 && blockIdx.x == 0) {
        double tprec = (ws[0] + 1.0) / (ws[1] + 1.0);
        double tsens = (ws[2] + 1.0) / (ws[3] + 1.0);
        double cl = 2.0 * tprec * tsens / (tprec + tsens + 1e-7);
        out[0] = (float)(1.0 - cl);
    }
}

extern "C" void kernel_launch(void* const* d_in, const int* in_sizes, int n_in,
                              void* d_out, int out_size, void* d_ws, size_t ws_size,
                              hipStream_t stream) {
    const float* pred   = (const float*)d_in[0];
    const float* target = (const float*)d_in[1];
    double* ws = (double*)d_ws;
    float* out = (float*)d_out;

    cldice_zero<<<dim3(1), dim3(64), 0, stream>>>(ws);
    cldice_main<<<dim3(NTILE, NTILE, 16), dim3(NTHREADS), 0, stream>>>(
        pred, target, ws);
    cldice_final<<<dim3(1), dim3(64), 0, stream>>>(ws, out);
}